// Round 1
// baseline (340.253 us; speedup 1.0000x reference)
//
#include <hip/hip_runtime.h>
#include <hip/hip_bf16.h>

// Problem constants (fixed by the reference)
#define N_ROWS 262144
#define IN_DIM 128
#define OUT_DIM 128
#define NTYPES 8
#define ROWS_PER_BLOCK 256
#define MAX_GROUPS 32   // worst case sum ceil(cnt_t/16) = 23 for 256 rows / 8 types

typedef short bf16x8 __attribute__((ext_vector_type(8)));   // 8 bf16 in 4 VGPRs (guide §3)
typedef float f32x4 __attribute__((ext_vector_type(4)));

__device__ __forceinline__ unsigned short f2bf_rne(float f) {
    unsigned int u = __float_as_uint(f);
    u += 0x7fff + ((u >> 16) & 1);   // round-nearest-even; inputs are finite/normal
    return (unsigned short)(u >> 16);
}

// Convert W [T][IN][OUT] fp32 -> Wb [T][OUT][IN] bf16 (B-operand friendly: k contiguous).
__global__ void prep_w_kernel(const float* __restrict__ W, unsigned short* __restrict__ Wb) {
    __shared__ float tile[128 * 129];   // +1 pad to break bank conflicts on transposed read
    const int t = blockIdx.x;
    const float* Wt = W + t * (IN_DIM * OUT_DIM);
    for (int e = threadIdx.x; e < IN_DIM * OUT_DIM; e += blockDim.x) {
        int i = e >> 7;     // in index
        int o = e & 127;    // out index
        tile[i * 129 + o] = Wt[e];
    }
    __syncthreads();
    unsigned short* Wbt = Wb + t * (IN_DIM * OUT_DIM);
    for (int e = threadIdx.x; e < IN_DIM * OUT_DIM; e += blockDim.x) {
        int o = e >> 7;
        int i = e & 127;
        Wbt[e] = f2bf_rne(tile[i * 129 + o]);   // coalesced write, conflict-free LDS read
    }
}

__global__ void __launch_bounds__(256) typed_linear_kernel(
        const float* __restrict__ x, const int* __restrict__ xt,
        const unsigned short* __restrict__ Wb, const float* __restrict__ bias,
        float* __restrict__ out) {
    __shared__ int s_cnt[NTYPES];
    __shared__ int s_cursor[NTYPES];
    __shared__ unsigned short s_list[ROWS_PER_BLOCK];   // row offsets grouped by type
    __shared__ unsigned char s_gtype[MAX_GROUPS];
    __shared__ short s_gstart[MAX_GROUPS];
    __shared__ unsigned char s_gcnt[MAX_GROUPS];
    __shared__ int s_ngroups;

    const int tid = threadIdx.x;
    const int row0 = blockIdx.x * ROWS_PER_BLOCK;

    // ---- Phase 1: bucket this block's 256 rows by type ----
    if (tid < NTYPES) s_cnt[tid] = 0;
    __syncthreads();
    const int my_t = xt[row0 + tid];
    atomicAdd(&s_cnt[my_t], 1);
    __syncthreads();
    if (tid == 0) {
        int acc = 0, g = 0;
        for (int i = 0; i < NTYPES; ++i) {
            int c = s_cnt[i];
            s_cursor[i] = acc;
            for (int s = 0; s < c; s += 16) {
                s_gtype[g] = (unsigned char)i;
                s_gstart[g] = (short)(acc + s);
                s_gcnt[g] = (unsigned char)((c - s) < 16 ? (c - s) : 16);
                ++g;
            }
            acc += c;
        }
        s_ngroups = g;
    }
    __syncthreads();
    {
        int pos = atomicAdd(&s_cursor[my_t], 1);
        s_list[pos] = (unsigned short)tid;
    }
    __syncthreads();

    // ---- Phase 2: MFMA over 16-row type-homogeneous groups ----
    const int wave = tid >> 6;
    const int lane = tid & 63;
    const int m = lane & 15;     // A row / B col / C col within 16-tile
    const int q = lane >> 4;     // quad id: k chunk = q*8.., C rows = q*4..q*4+3
    const int ngroups = s_ngroups;

    for (int g = wave; g < ngroups; g += 4) {
        const int t  = s_gtype[g];
        const int gs = s_gstart[g];
        const int gc = s_gcnt[g];

        // A fragments: 16 rows x K=128 (4 chunks of 32), fp32 -> bf16 packed cvt
        const int mm = (m < gc) ? m : (gc - 1);      // clamp padded lanes to a valid row
        const int arow = row0 + s_list[gs + mm];
        const float* xr = x + (size_t)arow * IN_DIM + q * 8;
        bf16x8 afrag[4];
        #pragma unroll
        for (int kc = 0; kc < 4; ++kc) {
            const float4 f0 = *reinterpret_cast<const float4*>(xr + kc * 32);
            const float4 f1 = *reinterpret_cast<const float4*>(xr + kc * 32 + 4);
            union { bf16x8 v; __hip_bfloat162 h[4]; } u;
            u.h[0] = __float22bfloat162_rn(make_float2(f0.x, f0.y));
            u.h[1] = __float22bfloat162_rn(make_float2(f0.z, f0.w));
            u.h[2] = __float22bfloat162_rn(make_float2(f1.x, f1.y));
            u.h[3] = __float22bfloat162_rn(make_float2(f1.z, f1.w));
            afrag[kc] = u.v;
        }

        // Output rows this lane stores (C layout: row = q*4+r, col = m)
        int orow[4];
        #pragma unroll
        for (int r = 0; r < 4; ++r) {
            const int mr = q * 4 + r;
            orow[r] = (mr < gc) ? (row0 + s_list[gs + mr]) : -1;
        }

        const unsigned short* wt = Wb + t * (IN_DIM * OUT_DIM);
        const float* bt = bias + t * OUT_DIM;
        #pragma unroll
        for (int nt = 0; nt < 8; ++nt) {
            f32x4 acc = {0.f, 0.f, 0.f, 0.f};
            const unsigned short* wcol = wt + (nt * 16 + m) * IN_DIM + q * 8;
            #pragma unroll
            for (int kc = 0; kc < 4; ++kc) {
                const bf16x8 bfrag = *reinterpret_cast<const bf16x8*>(wcol + kc * 32);
                acc = __builtin_amdgcn_mfma_f32_16x16x32_bf16(afrag[kc], bfrag, acc, 0, 0, 0);
            }
            const float bv = bt[nt * 16 + m];
            #pragma unroll
            for (int r = 0; r < 4; ++r) {
                if (orow[r] >= 0) {
                    out[(size_t)orow[r] * OUT_DIM + nt * 16 + m] = acc[r] + bv;
                }
            }
        }
    }
}

extern "C" void kernel_launch(void* const* d_in, const int* in_sizes, int n_in,
                              void* d_out, int out_size, void* d_ws, size_t ws_size,
                              hipStream_t stream) {
    const float* x  = (const float*)d_in[0];
    const int* xt   = (const int*)d_in[1];
    const float* W  = (const float*)d_in[2];
    const float* b  = (const float*)d_in[3];
    float* out      = (float*)d_out;
    unsigned short* Wb = (unsigned short*)d_ws;   // 8*128*128*2 = 256 KiB scratch

    prep_w_kernel<<<NTYPES, 256, 0, stream>>>(W, Wb);
    typed_linear_kernel<<<N_ROWS / ROWS_PER_BLOCK, 256, 0, stream>>>(x, xt, Wb, b, out);
}

// Round 2
// 319.382 us; speedup vs baseline: 1.0653x; 1.0653x over previous
//
#include <hip/hip_runtime.h>
#include <hip/hip_bf16.h>

// Problem constants (fixed by the reference)
#define N_ROWS 262144
#define IN_DIM 128
#define OUT_DIM 128
#define NTYPES 8
#define ROWS_PER_BLOCK 256
#define GROUP_M 32          // rows per group: two 16-row MFMA sub-tiles sharing B-frags
#define MAX_GROUPS 16       // sum ceil(c_t/32) <= 15 for 256 rows / 8 types

typedef short bf16x8 __attribute__((ext_vector_type(8)));   // 8 bf16 in 4 VGPRs
typedef float f32x4 __attribute__((ext_vector_type(4)));

__device__ __forceinline__ unsigned short f2bf_rne(float f) {
    unsigned int u = __float_as_uint(f);
    u += 0x7fff + ((u >> 16) & 1);   // round-nearest-even; inputs finite/normal
    return (unsigned short)(u >> 16);
}

// Convert W [T][IN][OUT] fp32 -> Wb [T][OUT][IN] bf16 (B-operand: k contiguous).
// 32 blocks: (type, 32-row in-slice). Each block: coalesced read -> LDS -> 64B-segment writes.
__global__ void prep_w_kernel(const float* __restrict__ W, unsigned short* __restrict__ Wb) {
    __shared__ float tile[32 * 129];   // +1 pad: conflict-free transposed read
    const int t = blockIdx.x >> 2;
    const int i0 = (blockIdx.x & 3) * 32;
    const float* Wt = W + t * (IN_DIM * OUT_DIM);
    for (int e = threadIdx.x; e < 32 * 128; e += blockDim.x) {
        int i = e >> 7;     // local in index (0..31)
        int o = e & 127;    // out index
        tile[i * 129 + o] = Wt[(i0 + i) * OUT_DIM + o];
    }
    __syncthreads();
    unsigned short* Wbt = Wb + t * (IN_DIM * OUT_DIM);
    for (int e = threadIdx.x; e < 32 * 128; e += blockDim.x) {
        int o = e >> 5;     // out index
        int i = e & 31;     // local in index -> consecutive lanes write consecutive bf16
        Wbt[o * IN_DIM + i0 + i] = f2bf_rne(tile[i * 129 + o]);
    }
}

__global__ void __launch_bounds__(256) typed_linear_kernel(
        const float* __restrict__ x, const int* __restrict__ xt,
        const unsigned short* __restrict__ Wb, const float* __restrict__ bias,
        float* __restrict__ out) {
    __shared__ int s_cnt[NTYPES];
    __shared__ int s_cursor[NTYPES];
    __shared__ unsigned short s_list[ROWS_PER_BLOCK];   // row offsets grouped by type
    __shared__ unsigned char s_gtype[MAX_GROUPS];
    __shared__ short s_gstart[MAX_GROUPS];
    __shared__ unsigned char s_gcnt[MAX_GROUPS];
    __shared__ int s_ngroups;

    const int tid = threadIdx.x;
    const int row0 = blockIdx.x * ROWS_PER_BLOCK;

    // ---- Phase 1: bucket this block's 256 rows by type ----
    if (tid < NTYPES) s_cnt[tid] = 0;
    __syncthreads();
    const int my_t = xt[row0 + tid];
    atomicAdd(&s_cnt[my_t], 1);
    __syncthreads();
    if (tid == 0) {
        int acc = 0, g = 0;
        for (int i = 0; i < NTYPES; ++i) {
            int c = s_cnt[i];
            s_cursor[i] = acc;
            for (int s = 0; s < c; s += GROUP_M) {
                s_gtype[g] = (unsigned char)i;
                s_gstart[g] = (short)(acc + s);
                s_gcnt[g] = (unsigned char)((c - s) < GROUP_M ? (c - s) : GROUP_M);
                ++g;
            }
            acc += c;
        }
        s_ngroups = g;
    }
    __syncthreads();
    {
        int pos = atomicAdd(&s_cursor[my_t], 1);
        s_list[pos] = (unsigned short)tid;
    }
    __syncthreads();

    // ---- Phase 2: MFMA over 32-row type-homogeneous groups ----
    const int wave = tid >> 6;
    const int lane = tid & 63;
    const int m = lane & 15;     // A row / B col / C col within 16-tile
    const int q = lane >> 4;     // quad id: k chunk = q*8.., C rows = q*4..q*4+3
    const int ngroups = s_ngroups;

    for (int g = wave; g < ngroups; g += 4) {
        const int t  = s_gtype[g];
        const int gs = s_gstart[g];
        const int gc = s_gcnt[g];

        // ---- A fragments for both 16-row sub-tiles: all loads independent ----
        bf16x8 afrag[2][4];
        #pragma unroll
        for (int sub = 0; sub < 2; ++sub) {
            const int mrow = sub * 16 + m;
            const int mm = (mrow < gc) ? mrow : (gc - 1);   // clamp padded lanes
            const float* xr = x + (size_t)(row0 + s_list[gs + mm]) * IN_DIM + q * 8;
            #pragma unroll
            for (int kc = 0; kc < 4; ++kc) {
                const float4 f0 = *reinterpret_cast<const float4*>(xr + kc * 32);
                const float4 f1 = *reinterpret_cast<const float4*>(xr + kc * 32 + 4);
                union { bf16x8 v; __hip_bfloat162 h[4]; } u;
                u.h[0] = __float22bfloat162_rn(make_float2(f0.x, f0.y));
                u.h[1] = __float22bfloat162_rn(make_float2(f0.z, f0.w));
                u.h[2] = __float22bfloat162_rn(make_float2(f1.x, f1.y));
                u.h[3] = __float22bfloat162_rn(make_float2(f1.z, f1.w));
                afrag[sub][kc] = u.v;
            }
        }

        // Output rows this lane stores (C layout: row = q*4+r, col = m)
        int orow[2][4];
        #pragma unroll
        for (int sub = 0; sub < 2; ++sub)
            #pragma unroll
            for (int r = 0; r < 4; ++r) {
                const int mr = sub * 16 + q * 4 + r;
                orow[sub][r] = (mr < gc) ? (row0 + s_list[gs + mr]) : -1;
            }

        const unsigned short* wt = Wb + t * (IN_DIM * OUT_DIM);
        const float* bt = bias + t * OUT_DIM;

        // ---- Two halves of 4 output-col tiles; B-frags batch-loaded per half ----
        #pragma unroll
        for (int half = 0; half < 2; ++half) {
            bf16x8 bfrag[4][4];
            #pragma unroll
            for (int nt2 = 0; nt2 < 4; ++nt2) {
                const int nt = half * 4 + nt2;
                const unsigned short* wcol = wt + (nt * 16 + m) * IN_DIM + q * 8;
                #pragma unroll
                for (int kc = 0; kc < 4; ++kc)
                    bfrag[nt2][kc] = *reinterpret_cast<const bf16x8*>(wcol + kc * 32);
            }
            #pragma unroll
            for (int nt2 = 0; nt2 < 4; ++nt2) {
                const int nt = half * 4 + nt2;
                f32x4 acc0 = {0.f, 0.f, 0.f, 0.f};
                f32x4 acc1 = {0.f, 0.f, 0.f, 0.f};
                #pragma unroll
                for (int kc = 0; kc < 4; ++kc) {
                    acc0 = __builtin_amdgcn_mfma_f32_16x16x32_bf16(afrag[0][kc], bfrag[nt2][kc], acc0, 0, 0, 0);
                    acc1 = __builtin_amdgcn_mfma_f32_16x16x32_bf16(afrag[1][kc], bfrag[nt2][kc], acc1, 0, 0, 0);
                }
                const float bv = bt[nt * 16 + m];
                #pragma unroll
                for (int r = 0; r < 4; ++r) {
                    if (orow[0][r] >= 0)
                        out[(size_t)orow[0][r] * OUT_DIM + nt * 16 + m] = acc0[r] + bv;
                    if (orow[1][r] >= 0)
                        out[(size_t)orow[1][r] * OUT_DIM + nt * 16 + m] = acc1[r] + bv;
                }
            }
        }
    }
}

extern "C" void kernel_launch(void* const* d_in, const int* in_sizes, int n_in,
                              void* d_out, int out_size, void* d_ws, size_t ws_size,
                              hipStream_t stream) {
    const float* x  = (const float*)d_in[0];
    const int* xt   = (const int*)d_in[1];
    const float* W  = (const float*)d_in[2];
    const float* b  = (const float*)d_in[3];
    float* out      = (float*)d_out;
    unsigned short* Wb = (unsigned short*)d_ws;   // 8*128*128*2 = 256 KiB scratch

    prep_w_kernel<<<NTYPES * 4, 256, 0, stream>>>(W, Wb);
    typed_linear_kernel<<<N_ROWS / ROWS_PER_BLOCK, 256, 0, stream>>>(x, xt, Wb, b, out);
}

// Round 3
// 308.105 us; speedup vs baseline: 1.1043x; 1.0366x over previous
//
#include <hip/hip_runtime.h>
#include <hip/hip_bf16.h>

// Problem constants (fixed by the reference)
#define N_ROWS 262144
#define IN_DIM 128
#define OUT_DIM 128
#define NTYPES 8
#define ROWS_PER_BLOCK 256
#define GROUP_M 16          // rows per MFMA group
#define MAX_GROUPS 32       // sum ceil(c_t/16) <= 23 for 256 rows / 8 types

typedef short bf16x8 __attribute__((ext_vector_type(8)));   // 8 bf16 in 4 VGPRs
typedef float f32x4 __attribute__((ext_vector_type(4)));

__device__ __forceinline__ unsigned short f2bf_rne(float f) {
    unsigned int u = __float_as_uint(f);
    u += 0x7fff + ((u >> 16) & 1);   // round-nearest-even; inputs finite/normal
    return (unsigned short)(u >> 16);
}

// Fire-and-forget 16B/lane global->LDS copy. Dest is wave-uniform base;
// HW lands lane L at base + L*16 (m97/m104 semantics).
__device__ __forceinline__ void async_copy16(const float* g, float* lds_base) {
    __builtin_amdgcn_global_load_lds(
        (const __attribute__((address_space(1))) void*)g,
        (__attribute__((address_space(3))) void*)lds_base,
        16, 0, 0);
}

// W [T][IN][OUT] fp32 -> Wb [T][OUT][IN] bf16. 1024 blocks x 128 threads:
// block (t,o), lane i: strided 4B reads (W is 512KB, L2/L3-resident), 2B
// contiguous writes. Wide grid so this kernel is ~2us.
__global__ void __launch_bounds__(128) prep_w_kernel(const float* __restrict__ W,
                                                     unsigned short* __restrict__ Wb) {
    const int t = blockIdx.x >> 7;
    const int o = blockIdx.x & 127;
    const int i = threadIdx.x;
    Wb[(t * OUT_DIM + o) * IN_DIM + i] = f2bf_rne(W[(t * IN_DIM + i) * OUT_DIM + o]);
}

__global__ void __launch_bounds__(256, 4) typed_linear_kernel(
        const float* __restrict__ x, const int* __restrict__ xt,
        const unsigned short* __restrict__ Wb, const float* __restrict__ bias,
        float* __restrict__ out) {
    // Per-wave 16x128 fp32 A-stage, XOR-swizzled: row m chunk c (16B chunks,
    // c in [0,32)) lives at physical chunk m*32 + (c^m). 4 waves x 8KB = 32KB.
    __shared__ float s_stage[4][2048];
    __shared__ int s_cnt[NTYPES];
    __shared__ int s_cursor[NTYPES];
    __shared__ unsigned short s_list[ROWS_PER_BLOCK];
    __shared__ unsigned char s_gtype[MAX_GROUPS];
    __shared__ short s_gstart[MAX_GROUPS];
    __shared__ unsigned char s_gcnt[MAX_GROUPS];
    __shared__ int s_ngroups;

    const int tid = threadIdx.x;
    const int row0 = blockIdx.x * ROWS_PER_BLOCK;

    // ---- Phase 1: bucket this block's 256 rows by type ----
    if (tid < NTYPES) s_cnt[tid] = 0;
    __syncthreads();
    const int my_t = xt[row0 + tid];
    atomicAdd(&s_cnt[my_t], 1);
    __syncthreads();
    if (tid == 0) {
        int acc = 0, g = 0;
        for (int i = 0; i < NTYPES; ++i) {
            int c = s_cnt[i];
            s_cursor[i] = acc;
            for (int s = 0; s < c; s += GROUP_M) {
                s_gtype[g] = (unsigned char)i;
                s_gstart[g] = (short)(acc + s);
                s_gcnt[g] = (unsigned char)((c - s) < GROUP_M ? (c - s) : GROUP_M);
                ++g;
            }
            acc += c;
        }
        s_ngroups = g;
    }
    __syncthreads();
    {
        int pos = atomicAdd(&s_cursor[my_t], 1);
        s_list[pos] = (unsigned short)tid;
    }
    __syncthreads();

    // ---- Phase 2: per-wave async-staged MFMA over 16-row groups ----
    const int wave = tid >> 6;
    const int lane = tid & 63;
    const int m = lane & 15;     // A row / B col / C col within 16-tile
    const int q = lane >> 4;     // quad: A k-chunk = q*8.., C rows = q*4..q*4+3
    const int l5 = lane >> 5;    // writer: which of the 2 rows per copy instr
    const int c_lo = lane & 31;  // writer: base chunk within row
    const int ngroups = s_ngroups;
    float* stage = s_stage[wave];

    for (int g = wave; g < ngroups; g += 4) {
        const int t  = s_gtype[g];
        const int gs = s_gstart[g];
        const int gc = s_gcnt[g];

        // Fire 8 async copies: instr j stages rows {2j, 2j+1}; lane L loads
        // row (2j + L/32) chunk ((L&31) ^ mrow) -> lands at phys chunk
        // j*64 + L = mrow*32 + (c ^ mrow). Source is 16B-aligned.
        #pragma unroll
        for (int j = 0; j < 8; ++j) {
            const int mrow = j * 2 + l5;
            const int mm = (mrow < gc) ? mrow : (gc - 1);   // clamp padded rows
            const int row = row0 + s_list[gs + mm];
            const int c = c_lo ^ mrow;                      // swizzle on logical row
            async_copy16(x + (size_t)row * IN_DIM + c * 4, stage + j * 256);
        }

        // Output rows this lane stores (C layout: row = q*4+r, col = m)
        int orow[4];
        #pragma unroll
        for (int r = 0; r < 4; ++r) {
            const int mr = q * 4 + r;
            orow[r] = (mr < gc) ? (row0 + s_list[gs + mr]) : -1;
        }

        const unsigned short* wt = Wb + t * (IN_DIM * OUT_DIM);
        const float* bt = bias + t * OUT_DIM;

        // Wait for this wave's staged A-tile (wave-private slot, no barrier).
        asm volatile("s_waitcnt vmcnt(0)" ::: "memory");

        // A fragments: lane (m,q) reads row m floats [kc*32+q*8, +8) as two
        // swizzled 16B chunks; cvt fp32->bf16 immediately to limit VGPR life.
        bf16x8 afrag[4];
        #pragma unroll
        for (int kc = 0; kc < 4; ++kc) {
            const int c0 = kc * 8 + q * 2;
            const float4 f0 = *reinterpret_cast<const float4*>(stage + (m * 32 + (c0 ^ m)) * 4);
            const float4 f1 = *reinterpret_cast<const float4*>(stage + (m * 32 + ((c0 + 1) ^ m)) * 4);
            union { bf16x8 v; __hip_bfloat162 h[4]; } u;
            u.h[0] = __float22bfloat162_rn(make_float2(f0.x, f0.y));
            u.h[1] = __float22bfloat162_rn(make_float2(f0.z, f0.w));
            u.h[2] = __float22bfloat162_rn(make_float2(f1.x, f1.y));
            u.h[3] = __float22bfloat162_rn(make_float2(f1.z, f1.w));
            afrag[kc] = u.v;
        }

        // 4 batches of 2 output-col tiles; B-frags (L2-resident) per batch.
        #pragma unroll
        for (int h = 0; h < 4; ++h) {
            bf16x8 bfrag[2][4];
            #pragma unroll
            for (int nn = 0; nn < 2; ++nn) {
                const int nt = h * 2 + nn;
                const unsigned short* wcol = wt + (nt * 16 + m) * IN_DIM + q * 8;
                #pragma unroll
                for (int kc = 0; kc < 4; ++kc)
                    bfrag[nn][kc] = *reinterpret_cast<const bf16x8*>(wcol + kc * 32);
            }
            #pragma unroll
            for (int nn = 0; nn < 2; ++nn) {
                const int nt = h * 2 + nn;
                f32x4 acc = {0.f, 0.f, 0.f, 0.f};
                #pragma unroll
                for (int kc = 0; kc < 4; ++kc)
                    acc = __builtin_amdgcn_mfma_f32_16x16x32_bf16(afrag[kc], bfrag[nn][kc], acc, 0, 0, 0);
                const float bv = bt[nt * 16 + m];
                #pragma unroll
                for (int r = 0; r < 4; ++r) {
                    if (orow[r] >= 0)
                        out[(size_t)orow[r] * OUT_DIM + nt * 16 + m] = acc[r] + bv;
                }
            }
        }
    }
}

extern "C" void kernel_launch(void* const* d_in, const int* in_sizes, int n_in,
                              void* d_out, int out_size, void* d_ws, size_t ws_size,
                              hipStream_t stream) {
    const float* x  = (const float*)d_in[0];
    const int* xt   = (const int*)d_in[1];
    const float* W  = (const float*)d_in[2];
    const float* b  = (const float*)d_in[3];
    float* out      = (float*)d_out;
    unsigned short* Wb = (unsigned short*)d_ws;   // 8*128*128*2 = 256 KiB scratch

    prep_w_kernel<<<NTYPES * OUT_DIM, 128, 0, stream>>>(W, Wb);
    typed_linear_kernel<<<N_ROWS / ROWS_PER_BLOCK, 256, 0, stream>>>(x, xt, Wb, b, out);
}